// Round 1
// baseline (504.191 us; speedup 1.0000x reference)
//
#include <hip/hip_runtime.h>
#include <cfloat>
#include <cmath>

#define MEM_DIM 2000
#define MPAD    2048
#define FEA     256
#define LAMBDA  0.0025f
#define HS_EPS  1e-12f

static const int Y_ELEMS = 16 * 256 * 1024;   // y output elements

// ---------------------------------------------------------------------------
// Kernel 0: transpose weight [2000][256] -> WT [256][2048] (zero-padded m)
// ---------------------------------------------------------------------------
__global__ __launch_bounds__(256) void k_transpose(const float* __restrict__ W,
                                                   float* __restrict__ WT) {
    __shared__ float tile[32][33];
    const int m0 = blockIdx.x * 32, c0 = blockIdx.y * 32;
    const int tx = threadIdx.x, ty = threadIdx.y;
#pragma unroll
    for (int i = 0; i < 4; ++i) {
        int m = m0 + ty + 8 * i;
        tile[ty + 8 * i][tx] = (m < MEM_DIM) ? W[m * FEA + c0 + tx] : 0.f;
    }
    __syncthreads();
#pragma unroll
    for (int i = 0; i < 4; ++i) {
        WT[(c0 + ty + 8 * i) * MPAD + m0 + tx] = tile[tx][ty + 8 * i];
    }
}

// ---------------------------------------------------------------------------
// Kernel 1: scores S[n][m] = x_row(n) . W[m]   (fp32, 128x128 tile, BK=32)
// S stored into att region laid out as [b][m][hw]  (exactly att_out layout)
// ---------------------------------------------------------------------------
__global__ __launch_bounds__(256) void k_scores(const float* __restrict__ x,
                                                const float* __restrict__ WT,
                                                float* __restrict__ S) {
    __shared__ float A[32][128];   // [k][row]
    __shared__ float B[32][128];   // [k][m]
    const int t   = threadIdx.x;
    const int m0  = blockIdx.x * 128;
    const int by  = blockIdx.y;            // 0..127 row tiles of 128
    const int b   = by >> 3;               // batch
    const int hw0 = (by & 7) << 7;         // hw offset (multiple of 128)
    const int tr  = t >> 4;                // 0..15 row quad-pair
    const int tm  = t & 15;                // 0..15 m quad-pair
    const int rq  = (t & 31) * 4;          // float4 lane within 128
    const int cg  = t >> 5;                // 0..7

    float acc[8][8] = {};

    for (int k0 = 0; k0 < FEA; k0 += 32) {
#pragma unroll
        for (int j = 0; j < 4; ++j) {
            int cl = cg + 8 * j;
            *(float4*)&A[cl][rq] =
                *(const float4*)&x[((b * FEA + k0 + cl) << 10) + hw0 + rq];
            *(float4*)&B[cl][rq] =
                *(const float4*)&WT[(k0 + cl) * MPAD + m0 + rq];
        }
        __syncthreads();
        for (int k = 0; k < 32; ++k) {
            float4 a0 = *(float4*)&A[k][8 * tr];
            float4 a1 = *(float4*)&A[k][8 * tr + 4];
            float4 b0 = *(float4*)&B[k][8 * tm];
            float4 b1 = *(float4*)&B[k][8 * tm + 4];
            float av[8] = {a0.x, a0.y, a0.z, a0.w, a1.x, a1.y, a1.z, a1.w};
            float bv[8] = {b0.x, b0.y, b0.z, b0.w, b1.x, b1.y, b1.z, b1.w};
#pragma unroll
            for (int i = 0; i < 8; ++i)
#pragma unroll
                for (int j = 0; j < 8; ++j)
                    acc[i][j] += av[i] * bv[j];
        }
        __syncthreads();
    }

    const int r0 = hw0 + 8 * tr;
#pragma unroll
    for (int j = 0; j < 8; ++j) {
        int m = m0 + 8 * tm + j;
        if (m < MEM_DIM) {
            float* p = &S[(size_t)((b * MEM_DIM + m) << 10) + r0];
            float4 v0 = {acc[0][j], acc[1][j], acc[2][j], acc[3][j]};
            float4 v1 = {acc[4][j], acc[5][j], acc[6][j], acc[7][j]};
            *(float4*)p       = v0;
            *(float4*)(p + 4) = v1;
        }
    }
}

// ---------------------------------------------------------------------------
// Kernel 2: per-row softmax + hard-shrink + L1 normalize, in place on S/att.
// Block = 512 threads: 16 float4-groups (64 rows) x 32 m-slots.
// ---------------------------------------------------------------------------
__global__ __launch_bounds__(512) void k_softmax(float* __restrict__ S) {
    __shared__ float4 red[32][16];
    const int t    = threadIdx.x;
    const int r4   = t & 15;          // which hw quad
    const int ms   = t >> 4;          // m slot 0..31
    const int beta = blockIdx.x;      // 0..255
    const int b    = beta >> 4;
    const int hw   = ((beta & 15) << 6) + 4 * r4;
    const size_t base = ((size_t)(b * MEM_DIM) << 10) + hw;

    // ---- pass 1: max ----
    float4 mx = make_float4(-FLT_MAX, -FLT_MAX, -FLT_MAX, -FLT_MAX);
    for (int m = ms; m < MEM_DIM; m += 32) {
        float4 v = *(const float4*)&S[base + ((size_t)m << 10)];
        mx.x = fmaxf(mx.x, v.x); mx.y = fmaxf(mx.y, v.y);
        mx.z = fmaxf(mx.z, v.z); mx.w = fmaxf(mx.w, v.w);
    }
    red[ms][r4] = mx;
    __syncthreads();
    float4 M = red[0][r4];
    for (int i = 1; i < 32; ++i) {
        float4 u = red[i][r4];
        M.x = fmaxf(M.x, u.x); M.y = fmaxf(M.y, u.y);
        M.z = fmaxf(M.z, u.z); M.w = fmaxf(M.w, u.w);
    }
    __syncthreads();

    // ---- pass 2: sum of exp ----
    float4 zs = make_float4(0.f, 0.f, 0.f, 0.f);
    for (int m = ms; m < MEM_DIM; m += 32) {
        float4 v = *(const float4*)&S[base + ((size_t)m << 10)];
        zs.x += expf(v.x - M.x); zs.y += expf(v.y - M.y);
        zs.z += expf(v.z - M.z); zs.w += expf(v.w - M.w);
    }
    red[ms][r4] = zs;
    __syncthreads();
    float4 Z = make_float4(0.f, 0.f, 0.f, 0.f);
    for (int i = 0; i < 32; ++i) {
        float4 u = red[i][r4];
        Z.x += u.x; Z.y += u.y; Z.z += u.z; Z.w += u.w;
    }
    __syncthreads();
    const float4 rZ = make_float4(1.f / Z.x, 1.f / Z.y, 1.f / Z.z, 1.f / Z.w);

    // ---- pass 3: shrink, write unnormalized, accumulate L1 ----
    float4 ds = make_float4(0.f, 0.f, 0.f, 0.f);
    for (int m = ms; m < MEM_DIM; m += 32) {
        float4 v = *(float4*)&S[base + ((size_t)m << 10)];
        {
            float a = expf(v.x - M.x) * rZ.x; float d = a - LAMBDA;
            float s = fmaxf(d, 0.f) * a / (fabsf(d) + HS_EPS); ds.x += s; v.x = s;
        }
        {
            float a = expf(v.y - M.y) * rZ.y; float d = a - LAMBDA;
            float s = fmaxf(d, 0.f) * a / (fabsf(d) + HS_EPS); ds.y += s; v.y = s;
        }
        {
            float a = expf(v.z - M.z) * rZ.z; float d = a - LAMBDA;
            float s = fmaxf(d, 0.f) * a / (fabsf(d) + HS_EPS); ds.z += s; v.z = s;
        }
        {
            float a = expf(v.w - M.w) * rZ.w; float d = a - LAMBDA;
            float s = fmaxf(d, 0.f) * a / (fabsf(d) + HS_EPS); ds.w += s; v.w = s;
        }
        *(float4*)&S[base + ((size_t)m << 10)] = v;
    }
    red[ms][r4] = ds;
    __syncthreads();
    float4 D = make_float4(0.f, 0.f, 0.f, 0.f);
    for (int i = 0; i < 32; ++i) {
        float4 u = red[i][r4];
        D.x += u.x; D.y += u.y; D.z += u.z; D.w += u.w;
    }
    const float4 rD = make_float4(1.f / fmaxf(D.x, HS_EPS), 1.f / fmaxf(D.y, HS_EPS),
                                  1.f / fmaxf(D.z, HS_EPS), 1.f / fmaxf(D.w, HS_EPS));

    // ---- pass 4: normalize (re-reads only this thread's own writes) ----
    for (int m = ms; m < MEM_DIM; m += 32) {
        float4 v = *(float4*)&S[base + ((size_t)m << 10)];
        v.x *= rD.x; v.y *= rD.y; v.z *= rD.z; v.w *= rD.w;
        *(float4*)&S[base + ((size_t)m << 10)] = v;
    }
}

// ---------------------------------------------------------------------------
// Kernel 3: y = att . W exploiting sparsity (ballot over nonzero att)
// ---------------------------------------------------------------------------
__global__ __launch_bounds__(256) void k_pv(const float* __restrict__ att,
                                            const float* __restrict__ W,
                                            float* __restrict__ y) {
    __shared__ float ylds[64][257];
    const int t    = threadIdx.x;
    const int beta = blockIdx.x;
    const int b    = beta >> 4;
    const int hw0  = (beta & 15) << 6;

    for (int i = t; i < 64 * 257; i += 256) ((float*)ylds)[i] = 0.f;
    __syncthreads();

    const int lane = t & 63, wv = t >> 6;
    const size_t base = ((size_t)(b * MEM_DIM) << 10) + hw0 + lane;

    for (int m = wv; m < MEM_DIM; m += 4) {
        float a = att[base + ((size_t)m << 10)];
        unsigned long long msk = __ballot(a != 0.f);
        while (msk) {
            int src = __ffsll((unsigned long long)msk) - 1;
            msk &= msk - 1;
            float av = __shfl(a, src);
            float4 w4 = *(const float4*)&W[m * FEA + lane * 4];
            float* yp = &ylds[src][lane * 4];
            atomicAdd(&yp[0], av * w4.x);
            atomicAdd(&yp[1], av * w4.y);
            atomicAdd(&yp[2], av * w4.z);
            atomicAdd(&yp[3], av * w4.w);
        }
    }
    __syncthreads();

    for (int c = wv; c < FEA; c += 4) {
        y[((b * FEA + c) << 10) + hw0 + lane] = ylds[lane][c];
    }
}

// ---------------------------------------------------------------------------
extern "C" void kernel_launch(void* const* d_in, const int* in_sizes, int n_in,
                              void* d_out, int out_size, void* d_ws, size_t ws_size,
                              hipStream_t stream) {
    const float* x = (const float*)d_in[0];
    const float* W = (const float*)d_in[1];
    float* out = (float*)d_out;
    float* y   = out;
    float* att = out + (size_t)Y_ELEMS;
    float* WT  = y;   // temp staging in y region; fully overwritten by k_pv

    k_transpose<<<dim3(64, 8), dim3(32, 8), 0, stream>>>(W, WT);
    k_scores  <<<dim3(16, 128), 256, 0, stream>>>(x, WT, att);
    k_softmax <<<256, 512, 0, stream>>>(att);
    k_pv      <<<256, 256, 0, stream>>>(att, W, y);
}

// Round 2
// 372.928 us; speedup vs baseline: 1.3520x; 1.3520x over previous
//
#include <hip/hip_runtime.h>
#include <cfloat>
#include <cmath>

#define MEM_DIM 2000
#define MPAD    2048
#define FEA     256
#define LAMBDA  0.0025f
#define HS_EPS  1e-12f

static const int Y_ELEMS = 16 * 256 * 1024;   // y output elements

// workspace layout (float offsets)
#define WS_WT 0          // [256][2048] fp32 W^T (zero-padded m)
#define WS_ZP 524288     // [16][16384] partial sum(e^z) per m-tile
#define WS_DP 786432     // [4][16384]  partial L1(s) per m-slice
// total ws use: (786432 + 65536) * 4 B ~= 3.33 MB

// ---------------------------------------------------------------------------
// Kernel 0: transpose weight [2000][256] -> WT [256][2048] (zero-padded m)
// ---------------------------------------------------------------------------
__global__ __launch_bounds__(256) void k_transpose(const float* __restrict__ W,
                                                   float* __restrict__ WT) {
    __shared__ float tile[32][33];
    const int m0 = blockIdx.x * 32, c0 = blockIdx.y * 32;
    const int tx = threadIdx.x, ty = threadIdx.y;
#pragma unroll
    for (int i = 0; i < 4; ++i) {
        int m = m0 + ty + 8 * i;
        tile[ty + 8 * i][tx] = (m < MEM_DIM) ? W[m * FEA + c0 + tx] : 0.f;
    }
    __syncthreads();
#pragma unroll
    for (int i = 0; i < 4; ++i) {
        WT[(c0 + ty + 8 * i) * MPAD + m0 + tx] = tile[tx][ty + 8 * i];
    }
}

// ---------------------------------------------------------------------------
// Kernel 1: scores z[n][m] = x_row(n) . W[m]  (fp32, 128x128 tile, BK=32,
// register-prefetch double-staging). Stores E = exp(z) into att region
// (layout [b][m][hw]) and per-row partial sums of e^z into zp planes.
// FMA order identical to round-1 kernel -> bit-identical logits.
// ---------------------------------------------------------------------------
__global__ __launch_bounds__(256) void k_scores(const float* __restrict__ x,
                                                const float* __restrict__ WT,
                                                float* __restrict__ S,
                                                float* __restrict__ zp) {
    __shared__ float A[32][128];   // [k][row]
    __shared__ float B[32][128];   // [k][m]
    const int t   = threadIdx.x;
    const int m0  = blockIdx.x * 128;
    const int by  = blockIdx.y;            // 0..127 row tiles of 128
    const int b   = by >> 3;               // batch
    const int hw0 = (by & 7) << 7;         // hw offset (multiple of 128)
    const int tr  = t >> 4;                // 0..15 row quad-pair
    const int tm  = t & 15;                // 0..15 m quad-pair
    const int rq  = (t & 31) * 4;          // float4 lane within 128
    const int cg  = t >> 5;                // 0..7

    float acc[8][8] = {};
    float4 pa[4], pb[4];

    // prologue: prefetch k0 = 0 chunk into registers
#pragma unroll
    for (int j = 0; j < 4; ++j) {
        int cl = cg + 8 * j;
        pa[j] = *(const float4*)&x[((b * FEA + cl) << 10) + hw0 + rq];
        pb[j] = *(const float4*)&WT[cl * MPAD + m0 + rq];
    }

    for (int k0 = 0; k0 < FEA; k0 += 32) {
        // stage current chunk registers -> LDS
#pragma unroll
        for (int j = 0; j < 4; ++j) {
            int cl = cg + 8 * j;
            *(float4*)&A[cl][rq] = pa[j];
            *(float4*)&B[cl][rq] = pb[j];
        }
        __syncthreads();
        // prefetch next chunk (latency hides under compute below)
        if (k0 + 32 < FEA) {
#pragma unroll
            for (int j = 0; j < 4; ++j) {
                int cl = k0 + 32 + cg + 8 * j;
                pa[j] = *(const float4*)&x[((b * FEA + cl) << 10) + hw0 + rq];
                pb[j] = *(const float4*)&WT[cl * MPAD + m0 + rq];
            }
        }
        for (int k = 0; k < 32; ++k) {
            float4 a0 = *(float4*)&A[k][8 * tr];
            float4 a1 = *(float4*)&A[k][8 * tr + 4];
            float4 b0 = *(float4*)&B[k][8 * tm];
            float4 b1 = *(float4*)&B[k][8 * tm + 4];
            float av[8] = {a0.x, a0.y, a0.z, a0.w, a1.x, a1.y, a1.z, a1.w};
            float bv[8] = {b0.x, b0.y, b0.z, b0.w, b1.x, b1.y, b1.z, b1.w};
#pragma unroll
            for (int i = 0; i < 8; ++i)
#pragma unroll
                for (int j = 0; j < 8; ++j)
                    acc[i][j] += av[i] * bv[j];
        }
        __syncthreads();
    }

    // epilogue: E = exp(z), store, accumulate per-row partial sums
    const int r0 = hw0 + 8 * tr;
    float p[8] = {0.f, 0.f, 0.f, 0.f, 0.f, 0.f, 0.f, 0.f};
#pragma unroll
    for (int j = 0; j < 8; ++j) {
        int m = m0 + 8 * tm + j;
        if (m < MEM_DIM) {
            float e0 = expf(acc[0][j]), e1 = expf(acc[1][j]);
            float e2 = expf(acc[2][j]), e3 = expf(acc[3][j]);
            float e4 = expf(acc[4][j]), e5 = expf(acc[5][j]);
            float e6 = expf(acc[6][j]), e7 = expf(acc[7][j]);
            p[0] += e0; p[1] += e1; p[2] += e2; p[3] += e3;
            p[4] += e4; p[5] += e5; p[6] += e6; p[7] += e7;
            float* ptr = &S[(size_t)((b * MEM_DIM + m) << 10) + r0];
            float4 v0 = {e0, e1, e2, e3};
            float4 v1 = {e4, e5, e6, e7};
            *(float4*)ptr       = v0;
            *(float4*)(ptr + 4) = v1;
        }
    }
    // reduce partials across the 16 tm lanes (same 16-lane group in-wave)
#pragma unroll
    for (int i = 0; i < 8; ++i) {
        float v = p[i];
        v += __shfl_xor(v, 1);
        v += __shfl_xor(v, 2);
        v += __shfl_xor(v, 4);
        v += __shfl_xor(v, 8);
        p[i] = v;
    }
    if ((t & 15) == 0) {
        float* zrow = zp + blockIdx.x * 16384 + b * 1024 + hw0 + 8 * tr;
#pragma unroll
        for (int i = 0; i < 8; ++i) zrow[i] = p[i];
    }
}

// ---------------------------------------------------------------------------
// Kernel 2: shrink. a = E / Z ; s = relu(a-l)*a/(|a-l|+eps) written in place.
// Partial L1 sums (over this block's 500-m slice) -> dp planes.
// Grid: 1024 blocks = 256 hw-chunks x 4 m-slices.
// ---------------------------------------------------------------------------
__global__ __launch_bounds__(256) void k_shrink(float* __restrict__ S,
                                                const float* __restrict__ zp,
                                                float* __restrict__ dp) {
    __shared__ float4 red[16][16];
    const int t     = threadIdx.x;
    const int hw4   = t & 15;          // hw quad
    const int ms    = t >> 4;          // m slot 0..15
    const int blk   = blockIdx.x;
    const int msl   = blk & 3;         // m slice
    const int chunk = blk >> 2;        // 0..255
    const int b     = chunk >> 4;
    const int hwl   = ((chunk & 15) << 6) + 4 * hw4;  // hw within batch
    const int row   = b * 1024 + hwl;
    const size_t base = ((size_t)(b * MEM_DIM) << 10) + hwl;

    // full-row Z = sum of 16 m-tile partials
    float4 Z = {0.f, 0.f, 0.f, 0.f};
#pragma unroll
    for (int mt = 0; mt < 16; ++mt) {
        float4 z4 = *(const float4*)&zp[mt * 16384 + row];
        Z.x += z4.x; Z.y += z4.y; Z.z += z4.z; Z.w += z4.w;
    }
    const float4 rZ = {1.f / Z.x, 1.f / Z.y, 1.f / Z.z, 1.f / Z.w};

    float4 D = {0.f, 0.f, 0.f, 0.f};
    const int lo = msl * 500, hi = lo + 500;
    for (int m = lo + ms; m < hi; m += 16) {
        float4 v = *(float4*)&S[base + ((size_t)m << 10)];
        {
            float a = v.x * rZ.x; float d = a - LAMBDA;
            float s = fmaxf(d, 0.f) * a / (fabsf(d) + HS_EPS); D.x += s; v.x = s;
        }
        {
            float a = v.y * rZ.y; float d = a - LAMBDA;
            float s = fmaxf(d, 0.f) * a / (fabsf(d) + HS_EPS); D.y += s; v.y = s;
        }
        {
            float a = v.z * rZ.z; float d = a - LAMBDA;
            float s = fmaxf(d, 0.f) * a / (fabsf(d) + HS_EPS); D.z += s; v.z = s;
        }
        {
            float a = v.w * rZ.w; float d = a - LAMBDA;
            float s = fmaxf(d, 0.f) * a / (fabsf(d) + HS_EPS); D.w += s; v.w = s;
        }
        *(float4*)&S[base + ((size_t)m << 10)] = v;
    }
    red[ms][hw4] = D;
    __syncthreads();
    if (t < 16) {
        float4 acc = red[0][t];
#pragma unroll
        for (int i = 1; i < 16; ++i) {
            float4 u = red[i][t];
            acc.x += u.x; acc.y += u.y; acc.z += u.z; acc.w += u.w;
        }
        *(float4*)&dp[msl * 16384 + b * 1024 + ((chunk & 15) << 6) + 4 * t] = acc;
    }
}

// ---------------------------------------------------------------------------
// Kernel 3: y = (s * rD) . W via sparsity ballot; normalize att in place
// (only nonzero entries need rewriting). 512 threads = 8 waves.
// ---------------------------------------------------------------------------
__global__ __launch_bounds__(512) void k_pv(float* __restrict__ att,
                                            const float* __restrict__ W,
                                            float* __restrict__ y,
                                            const float* __restrict__ dp) {
    __shared__ float ylds[64][257];
    const int t    = threadIdx.x;
    const int beta = blockIdx.x;
    const int b    = beta >> 4;
    const int hw0  = (beta & 15) << 6;

    for (int i = t; i < 64 * 257; i += 512) ((float*)ylds)[i] = 0.f;

    const int lane = t & 63, wv = t >> 6;
    const int row  = b * 1024 + hw0 + lane;
    float Dv = dp[row] + dp[16384 + row] + dp[2 * 16384 + row] + dp[3 * 16384 + row];
    const float rD = 1.f / fmaxf(Dv, HS_EPS);
    __syncthreads();

    const size_t base = ((size_t)(b * MEM_DIM) << 10) + hw0 + lane;

    for (int k0 = 0; k0 < 250; k0 += 5) {
        float a[5];
        int mm[5];
#pragma unroll
        for (int u = 0; u < 5; ++u) {
            mm[u] = wv + 8 * (k0 + u);
            a[u]  = att[base + ((size_t)mm[u] << 10)];
        }
#pragma unroll
        for (int u = 0; u < 5; ++u) {
            const float av = a[u];
            const int   m  = mm[u];
            unsigned long long msk = __ballot(av != 0.f);
            if (av != 0.f) att[base + ((size_t)m << 10)] = av * rD;
            while (msk) {
                int src = __ffsll(msk) - 1;
                msk &= msk - 1;
                float vs  = __shfl(av, src);
                float rDs = __shfl(rD, src);
                float v   = vs * rDs;
                float w0 = W[m * FEA + lane];
                float w1 = W[m * FEA + 64 + lane];
                float w2 = W[m * FEA + 128 + lane];
                float w3 = W[m * FEA + 192 + lane];
                atomicAdd(&ylds[src][lane],       v * w0);
                atomicAdd(&ylds[src][64 + lane],  v * w1);
                atomicAdd(&ylds[src][128 + lane], v * w2);
                atomicAdd(&ylds[src][192 + lane], v * w3);
            }
        }
    }
    __syncthreads();

    for (int c = wv; c < FEA; c += 8) {
        y[((b * FEA + c) << 10) + hw0 + lane] = ylds[lane][c];
    }
}

// ---------------------------------------------------------------------------
extern "C" void kernel_launch(void* const* d_in, const int* in_sizes, int n_in,
                              void* d_out, int out_size, void* d_ws, size_t ws_size,
                              hipStream_t stream) {
    const float* x = (const float*)d_in[0];
    const float* W = (const float*)d_in[1];
    float* out = (float*)d_out;
    float* y   = out;
    float* att = out + (size_t)Y_ELEMS;
    float* wsf = (float*)d_ws;
    float* WT  = wsf + WS_WT;
    float* zp  = wsf + WS_ZP;
    float* dp  = wsf + WS_DP;

    k_transpose<<<dim3(64, 8), dim3(32, 8), 0, stream>>>(W, WT);
    k_scores  <<<dim3(16, 128), 256, 0, stream>>>(x, WT, att, zp);
    k_shrink  <<<1024, 256, 0, stream>>>(att, zp, dp);
    k_pv      <<<256, 512, 0, stream>>>(att, W, y, dp);
}

// Round 3
// 238.011 us; speedup vs baseline: 2.1184x; 1.5669x over previous
//
#include <hip/hip_runtime.h>
#include <cfloat>
#include <cmath>

#define MEM_DIM 2000
#define FEA     256
#define LAMBDA  0.0025f
#define HS_EPS  1e-12f

typedef unsigned short u16;
typedef _Float16 f16x8  __attribute__((ext_vector_type(8)));
typedef float    f32x16 __attribute__((ext_vector_type(16)));

static const int Y_ELEMS = 16 * 256 * 1024;   // y output elements (16,777,216 B)

// workspace layout (float offsets): wsp u16[2][2048][256] = 2 MB at 0
#define WS_ZP 524288     // [16][16384] partial sum(e^z) per m-tile (1 MB)
#define WS_DP 786432     // [4][16384]  partial L1(s) per m-slice (0.25 MB)
// xs (f16 split of x, 16 MB) lives in the y output region (free until k_pv).

// ---------------------------------------------------------------------------
// Kernel A: split x [16][256][1024] f32 -> xs planes [2][16][1024][256] f16
// (transposed to hw-major, c contiguous). Plane1 = f16(x), plane2 = f16((x-hi)*256)
// ---------------------------------------------------------------------------
__global__ __launch_bounds__(256) void k_split_x(const float* __restrict__ x,
                                                 u16* __restrict__ xs) {
    __shared__ float tl[32][33];
    const int blk = blockIdx.x;           // 4096 = 16 b * 8 ct * 32 ht
    const int b   = blk >> 8;
    const int ct  = (blk >> 5) & 7;
    const int ht  = blk & 31;
    const int tx  = threadIdx.x & 31, ty = threadIdx.x >> 5;
#pragma unroll
    for (int i = 0; i < 4; ++i)
        tl[ty + 8 * i][tx] =
            x[(((b << 8) + (ct << 5) + ty + (i << 3)) << 10) + (ht << 5) + tx];
    __syncthreads();
#pragma unroll
    for (int i = 0; i < 4; ++i) {
        float v = tl[tx][ty + 8 * i];
        _Float16 a  = (_Float16)v;
        _Float16 bq = (_Float16)((v - (float)a) * 256.0f);
        const int hw = (ht << 5) + ty + (i << 3);
        const int c  = (ct << 5) + tx;
        const size_t o = (((size_t)(b << 10) + hw) << 8) + c;
        xs[o]           = *(u16*)&a;
        xs[4194304 + o] = *(u16*)&bq;
    }
}

// ---------------------------------------------------------------------------
// Kernel B: split W [2000][256] f32 -> wsp [2][2048][256] f16 (m zero-padded)
// ---------------------------------------------------------------------------
__global__ __launch_bounds__(256) void k_split_w(const float* __restrict__ W,
                                                 u16* __restrict__ wsp) {
    const int m = blockIdx.x;             // 2048
    const int c = threadIdx.x;
    float v = (m < MEM_DIM) ? W[(m << 8) + c] : 0.f;
    _Float16 a  = (_Float16)v;
    _Float16 bq = (_Float16)((v - (float)a) * 256.0f);
    wsp[(m << 8) + c]          = *(u16*)&a;
    wsp[524288 + (m << 8) + c] = *(u16*)&bq;
}

// ---------------------------------------------------------------------------
// Kernel 1: z = x.W^T via mfma_f32_32x32x16_f16, 2-split (3 passes, dual acc).
// Block: 128 rows x 128 m, BK=32, 4 waves (2x2), wave tile 64x64.
// LDS 32 KB: tiles A0,A1,B0,B1 each [128][32] f16, chunk-XOR swizzled.
// Staged by global_load_lds (linear dest, inverse-swizzled source).
// Epilogue: E=exp(z) -> S (att region, [b][m][1024]), row partial sums -> zp.
// ---------------------------------------------------------------------------
__global__ __launch_bounds__(256) void k_scores_mfma(
    const u16* __restrict__ xs, const u16* __restrict__ wsp,
    float* __restrict__ S, float* __restrict__ zp) {
    __shared__ u16 lds[16384];   // 32 KB
    const int t    = threadIdx.x;
    const int lane = t & 63;
    const int w    = t >> 6;
    const int wr   = w >> 1, wc = w & 1;
    const int lr   = lane & 31, lg = lane >> 5;

    const int bx  = blockIdx.x;
    const int wg  = ((bx & 7) << 8) | (bx >> 3);   // XCD swizzle (2048 = 8*256)
    const int m0t = wg & 15;
    const int rt  = wg >> 4;
    const int m0  = m0t << 7;
    const int b   = rt >> 3;
    const int hw0 = (rt & 7) << 7;

    // staging: 8 issues x 256 thr x 16 B = 32 KB. slot s -> tile(s>>9),
    // row r=(s&511)>>2, phys chunk cp=s&3 holds logical chunk cp^(r&3).
    const u16* gsrc[8];
    u16* ldst[8];
#pragma unroll
    for (int i = 0; i < 8; ++i) {
        const int s = (i << 8) + t;
        const int tile = s >> 9;
        const int u = s & 511;
        const int r = u >> 2;
        const int cl = (u & 3) ^ (r & 3);
        if (tile < 2)
            gsrc[i] = xs + tile * 4194304 + (((b << 10) + hw0 + r) << 8) + (cl << 3);
        else
            gsrc[i] = wsp + ((tile - 2) << 19) + ((m0 + r) << 8) + (cl << 3);
        ldst[i] = &lds[s << 3];
    }

    f32x16 acc1[2][2], acc2[2][2];
#pragma unroll
    for (int i = 0; i < 2; ++i)
#pragma unroll
        for (int j = 0; j < 2; ++j)
#pragma unroll
            for (int e = 0; e < 16; ++e) { acc1[i][j][e] = 0.f; acc2[i][j][e] = 0.f; }

    for (int kt = 0; kt < 8; ++kt) {
        __syncthreads();                      // previous tile fully consumed
#pragma unroll
        for (int i = 0; i < 8; ++i)
            __builtin_amdgcn_global_load_lds(
                (const __attribute__((address_space(1))) unsigned int*)(gsrc[i] + (kt << 5)),
                (__attribute__((address_space(3))) unsigned int*)ldst[i], 16, 0, 0);
        __syncthreads();                      // barrier drains vmcnt -> LDS ready
#pragma unroll
        for (int ks = 0; ks < 2; ++ks) {
            f16x8 a0[2], a1[2], b0[2], b1[2];
#pragma unroll
            for (int ri = 0; ri < 2; ++ri) {
                const int R  = (wr << 6) + (ri << 5) + lr;
                const int pc = ((ks << 1) + lg) ^ (R & 3);
                a0[ri] = *(const f16x8*)&lds[        (R << 5) + (pc << 3)];
                a1[ri] = *(const f16x8*)&lds[4096 +  (R << 5) + (pc << 3)];
            }
#pragma unroll
            for (int mi = 0; mi < 2; ++mi) {
                const int M  = (wc << 6) + (mi << 5) + lr;
                const int pc = ((ks << 1) + lg) ^ (M & 3);
                b0[mi] = *(const f16x8*)&lds[ 8192 + (M << 5) + (pc << 3)];
                b1[mi] = *(const f16x8*)&lds[12288 + (M << 5) + (pc << 3)];
            }
#pragma unroll
            for (int ri = 0; ri < 2; ++ri)
#pragma unroll
                for (int mi = 0; mi < 2; ++mi) {
                    acc2[ri][mi] = __builtin_amdgcn_mfma_f32_32x32x16_f16(a0[ri], b1[mi], acc2[ri][mi], 0, 0, 0);
                    acc2[ri][mi] = __builtin_amdgcn_mfma_f32_32x32x16_f16(a1[ri], b0[mi], acc2[ri][mi], 0, 0, 0);
                    acc1[ri][mi] = __builtin_amdgcn_mfma_f32_32x32x16_f16(a0[ri], b0[mi], acc1[ri][mi], 0, 0, 0);
                }
        }
    }

    __syncthreads();               // lds now reusable as reduction buffer
    float* zf = (float*)lds;

    float rs[2][16];
#pragma unroll
    for (int ri = 0; ri < 2; ++ri)
#pragma unroll
        for (int q = 0; q < 16; ++q) rs[ri][q] = 0.f;

#pragma unroll
    for (int ri = 0; ri < 2; ++ri)
#pragma unroll
        for (int mi = 0; mi < 2; ++mi) {
            const int m = m0 + (wc << 6) + (mi << 5) + lr;
            const bool valid = (m < MEM_DIM);
            float e[16];
#pragma unroll
            for (int q = 0; q < 16; ++q) {
                float z = acc1[ri][mi][q] + acc2[ri][mi][q] * 0.00390625f;
                e[q] = valid ? expf(z) : 0.f;
                rs[ri][q] += e[q];
            }
            if (valid) {
                const size_t pb = ((size_t)(b * MEM_DIM + m) << 10) + hw0
                                + (wr << 6) + (ri << 5) + (lg << 2);
#pragma unroll
                for (int q4 = 0; q4 < 4; ++q4) {
                    float4 v = {e[4 * q4], e[4 * q4 + 1], e[4 * q4 + 2], e[4 * q4 + 3]};
                    *(float4*)&S[pb + (q4 << 3)] = v;
                }
            }
        }

#pragma unroll
    for (int ri = 0; ri < 2; ++ri)
#pragma unroll
        for (int q = 0; q < 16; ++q) {
            float v = rs[ri][q];
            v += __shfl_xor(v, 1);
            v += __shfl_xor(v, 2);
            v += __shfl_xor(v, 4);
            v += __shfl_xor(v, 8);
            v += __shfl_xor(v, 16);
            rs[ri][q] = v;
        }
    if (lr == 0) {
#pragma unroll
        for (int ri = 0; ri < 2; ++ri)
#pragma unroll
            for (int q = 0; q < 16; ++q) {
                const int row = (wr << 6) + (ri << 5) + (q & 3) + ((q >> 2) << 3) + (lg << 2);
                zf[(wc << 7) + row] = rs[ri][q];
            }
    }
    __syncthreads();
    if (t < 128)
        zp[m0t * 16384 + (b << 10) + hw0 + t] = zf[t] + zf[128 + t];
}

// ---------------------------------------------------------------------------
// Kernel 2: shrink (unchanged from round 2)
// ---------------------------------------------------------------------------
__global__ __launch_bounds__(256) void k_shrink(float* __restrict__ S,
                                                const float* __restrict__ zp,
                                                float* __restrict__ dp) {
    __shared__ float4 red[16][16];
    const int t     = threadIdx.x;
    const int hw4   = t & 15;
    const int ms    = t >> 4;
    const int blk   = blockIdx.x;
    const int msl   = blk & 3;
    const int chunk = blk >> 2;
    const int b     = chunk >> 4;
    const int hwl   = ((chunk & 15) << 6) + 4 * hw4;
    const int row   = b * 1024 + hwl;
    const size_t base = ((size_t)(b * MEM_DIM) << 10) + hwl;

    float4 Z = {0.f, 0.f, 0.f, 0.f};
#pragma unroll
    for (int mt = 0; mt < 16; ++mt) {
        float4 z4 = *(const float4*)&zp[mt * 16384 + row];
        Z.x += z4.x; Z.y += z4.y; Z.z += z4.z; Z.w += z4.w;
    }
    const float4 rZ = {1.f / Z.x, 1.f / Z.y, 1.f / Z.z, 1.f / Z.w};

    float4 D = {0.f, 0.f, 0.f, 0.f};
    const int lo = msl * 500, hi = lo + 500;
    for (int m = lo + ms; m < hi; m += 16) {
        float4 v = *(float4*)&S[base + ((size_t)m << 10)];
        {
            float a = v.x * rZ.x; float d = a - LAMBDA;
            float s = fmaxf(d, 0.f) * a / (fabsf(d) + HS_EPS); D.x += s; v.x = s;
        }
        {
            float a = v.y * rZ.y; float d = a - LAMBDA;
            float s = fmaxf(d, 0.f) * a / (fabsf(d) + HS_EPS); D.y += s; v.y = s;
        }
        {
            float a = v.z * rZ.z; float d = a - LAMBDA;
            float s = fmaxf(d, 0.f) * a / (fabsf(d) + HS_EPS); D.z += s; v.z = s;
        }
        {
            float a = v.w * rZ.w; float d = a - LAMBDA;
            float s = fmaxf(d, 0.f) * a / (fabsf(d) + HS_EPS); D.w += s; v.w = s;
        }
        *(float4*)&S[base + ((size_t)m << 10)] = v;
    }
    red[ms][hw4] = D;
    __syncthreads();
    if (t < 16) {
        float4 acc = red[0][t];
#pragma unroll
        for (int i = 1; i < 16; ++i) {
            float4 u = red[i][t];
            acc.x += u.x; acc.y += u.y; acc.z += u.z; acc.w += u.w;
        }
        *(float4*)&dp[msl * 16384 + b * 1024 + ((chunk & 15) << 6) + 4 * t] = acc;
    }
}

// ---------------------------------------------------------------------------
// Kernel 3: sparse PV + in-place normalize (unchanged from round 2)
// ---------------------------------------------------------------------------
__global__ __launch_bounds__(512) void k_pv(float* __restrict__ att,
                                            const float* __restrict__ W,
                                            float* __restrict__ y,
                                            const float* __restrict__ dp) {
    __shared__ float ylds[64][257];
    const int t    = threadIdx.x;
    const int beta = blockIdx.x;
    const int b    = beta >> 4;
    const int hw0  = (beta & 15) << 6;

    for (int i = t; i < 64 * 257; i += 512) ((float*)ylds)[i] = 0.f;

    const int lane = t & 63, wv = t >> 6;
    const int row  = b * 1024 + hw0 + lane;
    float Dv = dp[row] + dp[16384 + row] + dp[2 * 16384 + row] + dp[3 * 16384 + row];
    const float rD = 1.f / fmaxf(Dv, HS_EPS);
    __syncthreads();

    const size_t base = ((size_t)(b * MEM_DIM) << 10) + hw0 + lane;

    for (int k0 = 0; k0 < 250; k0 += 5) {
        float a[5];
        int mm[5];
#pragma unroll
        for (int u = 0; u < 5; ++u) {
            mm[u] = wv + 8 * (k0 + u);
            a[u]  = att[base + ((size_t)mm[u] << 10)];
        }
#pragma unroll
        for (int u = 0; u < 5; ++u) {
            const float av = a[u];
            const int   m  = mm[u];
            unsigned long long msk = __ballot(av != 0.f);
            if (av != 0.f) att[base + ((size_t)m << 10)] = av * rD;
            while (msk) {
                int src = __ffsll(msk) - 1;
                msk &= msk - 1;
                float vs  = __shfl(av, src);
                float rDs = __shfl(rD, src);
                float v   = vs * rDs;
                float w0 = W[m * FEA + lane];
                float w1 = W[m * FEA + 64 + lane];
                float w2 = W[m * FEA + 128 + lane];
                float w3 = W[m * FEA + 192 + lane];
                atomicAdd(&ylds[src][lane],       v * w0);
                atomicAdd(&ylds[src][64 + lane],  v * w1);
                atomicAdd(&ylds[src][128 + lane], v * w2);
                atomicAdd(&ylds[src][192 + lane], v * w3);
            }
        }
    }
    __syncthreads();

    for (int c = wv; c < FEA; c += 8) {
        y[((b * FEA + c) << 10) + hw0 + lane] = ylds[lane][c];
    }
}

// ---------------------------------------------------------------------------
extern "C" void kernel_launch(void* const* d_in, const int* in_sizes, int n_in,
                              void* d_out, int out_size, void* d_ws, size_t ws_size,
                              hipStream_t stream) {
    const float* x = (const float*)d_in[0];
    const float* W = (const float*)d_in[1];
    float* out = (float*)d_out;
    float* y   = out;
    float* att = out + (size_t)Y_ELEMS;
    float* wsf = (float*)d_ws;
    u16*   wsp = (u16*)d_ws;                 // 2 MB
    float* zp  = wsf + WS_ZP;
    float* dp  = wsf + WS_DP;
    u16*   xs  = (u16*)y;                    // 16 MB staging in y region
                                             // (consumed before k_pv writes y)

    k_split_x    <<<4096, 256, 0, stream>>>(x, xs);
    k_split_w    <<<2048, 256, 0, stream>>>(W, wsp);
    k_scores_mfma<<<2048, 256, 0, stream>>>(xs, wsp, att, zp);
    k_shrink     <<<1024, 256, 0, stream>>>(att, zp, dp);
    k_pv         <<<256, 512, 0, stream>>>(att, W, y, dp);
}